// Round 7
// baseline (1408.947 us; speedup 1.0000x reference)
//
#include <hip/hip_runtime.h>
#include <hip/hip_fp16.h>
#include <cmath>

#define NHEAD 3
#define HD 96          // H * D = 3 * 32
#define DOUT 32
#define SLOPE 0.01f
#define BN_EPS 1e-5f

static constexpr int NN = 100000;   // NU == NI == 100000
static constexpr int Ec = 500000;
static constexpr int SCB = (NN + 255) / 256;   // 391 chunks per relation

// ---------------- job structs ----------------
struct TJob { const float* X; const float* W; const float* Wsm; const float* bias; void* outF; float* outE; };
struct AWJob { const float* W; const float* a; float* out; int din; };
struct AWJobs { AWJob j[8]; };

// ---------------- attn-weight pre-reduction ----------------
__global__ __launch_bounds__(192)
void attw_k(AWJobs js) {
    AWJob jb = js.j[blockIdx.x];
    const int t = threadIdx.x;
    const int k = t / 3, h = t - 3 * (t / 3);
    if (k < jb.din) {
        const float* wrow = jb.W + (size_t)k * HD + h * 32;
        const float* av = jb.a + h * 32;
        float s = 0.f;
        #pragma unroll
        for (int d = 0; d < 32; ++d) s = fmaf(wrow[d], av[d], s);
        jb.out[k * 3 + h] = s;
    }
}

// ---------------- CSR build ----------------
__global__ void zero_k(int* p, int n) {
    const int i = blockIdx.x * 256 + threadIdx.x;
    if (i < n) p[i] = 0;
}

__global__ void hist_k(const int* __restrict__ gd, const int* __restrict__ bd, int* __restrict__ cnt) {
    const int i = blockIdx.x * 256 + threadIdx.x;
    if (i < Ec) atomicAdd(&cnt[gd[i]], 1);
    else if (i < 2 * Ec) atomicAdd(&cnt[NN + bd[i - Ec]], 1);
}

__global__ __launch_bounds__(256)
void scan_a_k(const int* __restrict__ cnt, int* __restrict__ bsum) {
    const int rel = blockIdx.y, blk = blockIdx.x;
    const int i = blk * 256 + threadIdx.x;
    int v = (i < NN) ? cnt[rel * NN + i] : 0;
    #pragma unroll
    for (int d = 32; d; d >>= 1) v += __shfl_xor(v, d);
    __shared__ int ws[4];
    const int lane = threadIdx.x & 63, wid = threadIdx.x >> 6;
    if (lane == 0) ws[wid] = v;
    __syncthreads();
    if (threadIdx.x == 0) bsum[rel * SCB + blk] = ws[0] + ws[1] + ws[2] + ws[3];
}

__global__ __launch_bounds__(512)
void scan_b_k(int* __restrict__ bsum, int* __restrict__ off) {
    const int rel = blockIdx.x;
    __shared__ int ps[512];
    const int t = threadIdx.x;
    const int v = (t < SCB) ? bsum[rel * SCB + t] : 0;
    ps[t] = v;
    __syncthreads();
    for (int d = 1; d < 512; d <<= 1) {
        const int u = (t >= d) ? ps[t - d] : 0;
        __syncthreads();
        ps[t] += u;
        __syncthreads();
    }
    if (t < SCB) bsum[rel * SCB + t] = ps[t] - v;
    if (t == SCB - 1) off[rel * (NN + 1) + NN] = ps[t];
}

__global__ __launch_bounds__(256)
void scan_c_k(int* __restrict__ cnt, const int* __restrict__ bsum, int* __restrict__ off) {
    const int rel = blockIdx.y, blk = blockIdx.x;
    const int t = threadIdx.x;
    const int i = blk * 256 + t;
    const int v = (i < NN) ? cnt[rel * NN + i] : 0;
    const int lane = t & 63, wid = t >> 6;
    int incl = v;
    #pragma unroll
    for (int d = 1; d < 64; d <<= 1) {
        const int u = __shfl_up(incl, d);
        if (lane >= d) incl += u;
    }
    __shared__ int wsum[4];
    if (lane == 63) wsum[wid] = incl;
    __syncthreads();
    int base = 0;
    #pragma unroll
    for (int w = 0; w < 4; ++w) base += (w < wid) ? wsum[w] : 0;
    if (i < NN) {
        off[rel * (NN + 1) + i] = bsum[rel * SCB + blk] + base + incl - v;
        cnt[rel * NN + i] = 0;
    }
}

__global__ void fill_k(const int* __restrict__ gs, const int* __restrict__ gd,
                       const int* __restrict__ bs, const int* __restrict__ bd,
                       const int* __restrict__ off, int* __restrict__ cur, int* __restrict__ csr) {
    const int i = blockIdx.x * 256 + threadIdx.x;
    if (i < Ec) {
        const int d = gd[i];
        const int p = off[d] + atomicAdd(&cur[d], 1);
        csr[p] = gs[i];
    } else if (i < 2 * Ec) {
        const int d = bd[i - Ec];
        const int p = off[(NN + 1) + d] + atomicAdd(&cur[NN + d], 1);
        csr[Ec + p] = bs[i - Ec];
    }
}

// ---------------- dense transform v3: X row in regs ONCE, 3 explicit 32-wide acc tiles ----------------
// jA (blockIdx.y==0): outF = fp16-packed messages. jB: outF = fp32 acc (res@W + bias).
template<int DIN>
__global__ __launch_bounds__(256)
void transform_k(TJob jA, TJob jB, int N) {
    const bool isA = (blockIdx.y == 0);
    const TJob j = isA ? jA : jB;
    const int n = blockIdx.x * 256 + threadIdx.x;
    if (n >= N) return;
    const float* __restrict__ Wg  = j.W;
    const float* __restrict__ Wsm = j.Wsm;
    const float* __restrict__ bs  = j.bias;

    // X row once into registers
    float xr[DIN];
    {
        const float4* __restrict__ xrow = reinterpret_cast<const float4*>(j.X + (size_t)n * DIN);
        #pragma unroll
        for (int kk = 0; kk < DIN / 4; ++kk) {
            const float4 v = xrow[kk];
            xr[kk * 4 + 0] = v.x; xr[kk * 4 + 1] = v.y; xr[kk * 4 + 2] = v.z; xr[kk * 4 + 3] = v.w;
        }
    }

    // attention dots
    float e0 = 0.f, e1 = 0.f, e2 = 0.f;
    #pragma unroll 4
    for (int k = 0; k < DIN; ++k) {
        const float x = xr[k];
        e0 = fmaf(x, Wsm[k * 3 + 0], e0);
        e1 = fmaf(x, Wsm[k * 3 + 1], e1);
        e2 = fmaf(x, Wsm[k * 3 + 2], e2);
    }
    j.outE[(size_t)n * 3 + 0] = e0;
    j.outE[(size_t)n * 3 + 1] = e1;
    j.outE[(size_t)n * 3 + 2] = e2;

    // 3 output tiles of 32, register-resident accumulator
    #pragma unroll 1
    for (int t3 = 0; t3 < 3; ++t3) {
        float acct[32];
        if (bs) {
            #pragma unroll
            for (int o = 0; o < 32; ++o) acct[o] = bs[t3 * 32 + o];   // uniform -> s_load
        } else {
            #pragma unroll
            for (int o = 0; o < 32; ++o) acct[o] = 0.f;
        }
        #pragma unroll 2
        for (int k = 0; k < DIN; ++k) {
            const float x = xr[k];
            const float* __restrict__ wk = Wg + (size_t)k * HD + t3 * 32;
            #pragma unroll
            for (int o = 0; o < 32; ++o)
                acct[o] = fmaf(x, wk[o], acct[o]);                     // W uniform -> s_load
        }
        if (isA) {
            unsigned int* __restrict__ op = (unsigned int*)j.outF + (size_t)n * 48 + t3 * 16;
            #pragma unroll
            for (int o = 0; o < 32; o += 8) {
                uint4 u;
                u.x = __builtin_bit_cast(unsigned int, __float22half2_rn(make_float2(acct[o    ], acct[o + 1])));
                u.y = __builtin_bit_cast(unsigned int, __float22half2_rn(make_float2(acct[o + 2], acct[o + 3])));
                u.z = __builtin_bit_cast(unsigned int, __float22half2_rn(make_float2(acct[o + 4], acct[o + 5])));
                u.w = __builtin_bit_cast(unsigned int, __float22half2_rn(make_float2(acct[o + 6], acct[o + 7])));
                *reinterpret_cast<uint4*>(op + o / 2) = u;
            }
        } else {
            float* __restrict__ op = (float*)j.outF + (size_t)n * HD + t3 * 32;
            #pragma unroll
            for (int o = 0; o < 32; o += 4) {
                float4 v; v.x = acct[o]; v.y = acct[o + 1]; v.z = acct[o + 2]; v.w = acct[o + 3];
                *reinterpret_cast<float4*>(op + o) = v;
            }
        }
    }
}

// ---------------- fused softmax + aggregation + linear + BN + ReLU ----------------
// Block = 4 waves = 4 dst nodes. Phase1: per-wave softmax (per-lane edge regs),
// gather via SHFL-broadcast indices/weights (no LDS in the chain), fp16 messages,
// + residual -> xLDS. Phase2: 128 threads do (4 nodes x 32) linear + BN + ReLU.
__global__ __launch_bounds__(256)
void agg_lin_k(const int* __restrict__ off, const int* __restrict__ srcs,
               const float* __restrict__ el, const float* __restrict__ er,
               const __half2* __restrict__ fsh, const float* __restrict__ accres,
               const float* __restrict__ Wl, const float* __restrict__ bl,
               const float* __restrict__ bn, float* __restrict__ out, int N)
{
    __shared__ float xLDS[4][100];  // aggregated 96-vector per node (+pad)

    const int wid  = threadIdx.x >> 6;
    const int lane = threadIdx.x & 63;
    const int node = blockIdx.x * 4 + wid;

    if (node < N) {
        const int o0 = off[node], o1 = off[node + 1];
        const int deg = o1 - o0;
        const float er0 = er[node * 3 + 0], er1 = er[node * 3 + 1], er2 = er[node * 3 + 2];
        const int h2 = lane >> 4;          // head for channel pair (2*lane, 2*lane+1), lane<48
        float a0 = 0.f, a1 = 0.f;

        if (deg <= 64) {
            // ---- fast path: 1 edge per lane, all state in registers ----
            const int p = o0 + lane;
            const bool has = p < o1;
            const int s = has ? srcs[p] : 0;
            float v0 = -INFINITY, v1 = -INFINITY, v2 = -INFINITY;
            if (has) {
                v0 = el[s * 3 + 0] + er0; v0 = v0 > 0.f ? v0 : SLOPE * v0;
                v1 = el[s * 3 + 1] + er1; v1 = v1 > 0.f ? v1 : SLOPE * v1;
                v2 = el[s * 3 + 2] + er2; v2 = v2 > 0.f ? v2 : SLOPE * v2;
            }
            float m0 = v0, m1 = v1, m2 = v2;
            #pragma unroll
            for (int d = 32; d; d >>= 1) {
                m0 = fmaxf(m0, __shfl_xor(m0, d));
                m1 = fmaxf(m1, __shfl_xor(m1, d));
                m2 = fmaxf(m2, __shfl_xor(m2, d));
            }
            const float e0x = has ? __expf(v0 - m0) : 0.f;
            const float e1x = has ? __expf(v1 - m1) : 0.f;
            const float e2x = has ? __expf(v2 - m2) : 0.f;
            float s0 = e0x, s1 = e1x, s2 = e2x;
            #pragma unroll
            for (int d = 32; d; d >>= 1) {
                s0 += __shfl_xor(s0, d); s1 += __shfl_xor(s1, d); s2 += __shfl_xor(s2, d);
            }
            const float w0 = e0x * (s0 > 0.f ? 1.f / s0 : 0.f);
            const float w1 = e1x * (s1 > 0.f ? 1.f / s1 : 0.f);
            const float w2 = e2x * (s2 > 0.f ? 1.f / s2 : 0.f);
            // serial over edges; index+weight via shfl (register crossbar, loads pipeline)
            #pragma unroll 2
            for (int jj = 0; jj < deg; ++jj) {
                const int   sj = __shfl(s,  jj);
                const float t0 = __shfl(w0, jj);
                const float t1 = __shfl(w1, jj);
                const float t2 = __shfl(w2, jj);
                const float wgt = (h2 == 0) ? t0 : (h2 == 1) ? t1 : t2;
                if (lane < 48) {
                    const float2 f = __half22float2(fsh[(size_t)sj * 48 + lane]);
                    a0 = fmaf(f.x, wgt, a0);
                    a1 = fmaf(f.y, wgt, a1);
                }
            }
        } else {
            // ---- generic path (deg > 64), rare ----
            float m0 = -INFINITY, m1 = -INFINITY, m2 = -INFINITY;
            for (int p = o0 + lane; p < o1; p += 64) {
                const int s = srcs[p];
                float v0 = el[s * 3 + 0] + er0; v0 = v0 > 0.f ? v0 : SLOPE * v0;
                float v1 = el[s * 3 + 1] + er1; v1 = v1 > 0.f ? v1 : SLOPE * v1;
                float v2 = el[s * 3 + 2] + er2; v2 = v2 > 0.f ? v2 : SLOPE * v2;
                m0 = fmaxf(m0, v0); m1 = fmaxf(m1, v1); m2 = fmaxf(m2, v2);
            }
            #pragma unroll
            for (int d = 32; d; d >>= 1) {
                m0 = fmaxf(m0, __shfl_xor(m0, d));
                m1 = fmaxf(m1, __shfl_xor(m1, d));
                m2 = fmaxf(m2, __shfl_xor(m2, d));
            }
            float s0 = 0.f, s1 = 0.f, s2 = 0.f;
            for (int p = o0 + lane; p < o1; p += 64) {
                const int s = srcs[p];
                float v0 = el[s * 3 + 0] + er0; v0 = v0 > 0.f ? v0 : SLOPE * v0;
                float v1 = el[s * 3 + 1] + er1; v1 = v1 > 0.f ? v1 : SLOPE * v1;
                float v2 = el[s * 3 + 2] + er2; v2 = v2 > 0.f ? v2 : SLOPE * v2;
                s0 += __expf(v0 - m0); s1 += __expf(v1 - m1); s2 += __expf(v2 - m2);
            }
            #pragma unroll
            for (int d = 32; d; d >>= 1) {
                s0 += __shfl_xor(s0, d); s1 += __shfl_xor(s1, d); s2 += __shfl_xor(s2, d);
            }
            const float r0 = s0 > 0.f ? 1.f / s0 : 0.f;
            const float r1 = s1 > 0.f ? 1.f / s1 : 0.f;
            const float r2 = s2 > 0.f ? 1.f / s2 : 0.f;
            if (lane < 48) {
                const float erh = (h2 == 0) ? er0 : (h2 == 1) ? er1 : er2;
                const float mh  = (h2 == 0) ? m0  : (h2 == 1) ? m1  : m2;
                const float rh  = (h2 == 0) ? r0  : (h2 == 1) ? r1  : r2;
                for (int p = o0; p < o1; ++p) {
                    const int s = srcs[p];
                    float v = el[s * 3 + h2] + erh; v = v > 0.f ? v : SLOPE * v;
                    const float wgt = __expf(v - mh) * rh;
                    const float2 f = __half22float2(fsh[(size_t)s * 48 + lane]);
                    a0 = fmaf(f.x, wgt, a0);
                    a1 = fmaf(f.y, wgt, a1);
                }
            }
        }
        if (lane < 48) {
            const float2 rv = *reinterpret_cast<const float2*>(&accres[(size_t)node * HD + 2 * lane]);
            float2 xv; xv.x = a0 + rv.x; xv.y = a1 + rv.y;
            *reinterpret_cast<float2*>(&xLDS[wid][2 * lane]) = xv;
        }
    }
    __syncthreads();

    // ---- phase 2: linear(96->32) + BN + ReLU, 128 threads = 4 nodes x 32 outputs ----
    const int t = threadIdx.x;
    if (t < 128) {
        const int nd = t >> 5, o = t & 31;
        const int node2 = blockIdx.x * 4 + nd;
        if (node2 < N) {
            float y = bl[o];
            const float* xr = xLDS[nd];
            #pragma unroll 4
            for (int k = 0; k < HD; ++k)
                y = fmaf(xr[k], Wl[k * DOUT + o], y);
            const float gamma = bn[o], beta = bn[DOUT + o], mean = bn[2 * DOUT + o], var = bn[3 * DOUT + o];
            const float r = (y - mean) * gamma * rsqrtf(var + BN_EPS) + beta;
            out[(size_t)node2 * DOUT + o] = fmaxf(r, 0.f);
        }
    }
}

// ---------------- host ----------------
extern "C" void kernel_launch(void* const* d_in, const int* in_sizes, int n_in,
                              void* d_out, int out_size, void* d_ws, size_t ws_size,
                              hipStream_t stream)
{
    const float* emb_user = (const float*)d_in[0];
    const float* emb_item = (const float*)d_in[1];
    const float* W1    = (const float*)d_in[2];
    const float* attn1 = (const float*)d_in[3];
    const float* res1  = (const float*)d_in[4];
    const float* bias1 = (const float*)d_in[5];
    const float* nnW1  = (const float*)d_in[6];
    const float* nnb1  = (const float*)d_in[7];
    const float* bn1   = (const float*)d_in[8];
    const float* W2    = (const float*)d_in[9];
    const float* attn2 = (const float*)d_in[10];
    const float* res2  = (const float*)d_in[11];
    const float* bias2 = (const float*)d_in[12];
    const float* nnW2  = (const float*)d_in[13];
    const float* nnb2  = (const float*)d_in[14];
    const float* bn2   = (const float*)d_in[15];
    const int* go_src   = (const int*)d_in[16];
    const int* go_dst   = (const int*)d_in[17];
    const int* back_src = (const int*)d_in[18];
    const int* back_dst = (const int*)d_in[19];

    // workspace layout (~91 MB)
    int* icnt = (int*)d_ws;                    // 2*NN
    int* ioff = icnt + 2 * NN;                 // 2*(NN+1)
    int* icsr = ioff + 2 * (NN + 1);           // 2*Ec
    int* ibs  = icsr + 2 * Ec;                 // 2*SCB
    float* aw = (float*)((int*)d_ws + 1400800);// 8*192 attn weights (+pad)
    float* fsraw = aw + 2048;                  // NN*96 halves = NN*48 float-slots
    __half2* fsh = (__half2*)fsraw;
    float* acc = fsraw + (size_t)NN * 48;      // NN*96 fp32 (residual base)
    float* el  = acc + (size_t)NN * HD;        // NN*3
    float* er  = el + (size_t)NN * 3;          // NN*3
    float* hu1 = er + (size_t)NN * 3;          // NN*32
    float* hi1 = hu1 + (size_t)NN * DOUT;      // NN*32

    float* out_user = (float*)d_out;
    float* out_item = out_user + (size_t)NN * DOUT;

    // 1) attention pre-reduction
    {
        const float* Wm[4] = { W1, W1 + 64 * HD, W2, W2 + 32 * HD };
        const float* Am[4] = { attn1, attn1 + 192, attn2, attn2 + 192 };
        const int dins[4] = { 64, 64, 32, 32 };
        AWJobs js;
        for (int r = 0; r < 4; ++r)
            for (int s = 0; s < 2; ++s)
                js.j[r * 2 + s] = { Wm[r], Am[r] + s * HD, aw + (size_t)(r * 2 + s) * 192, dins[r] };
        attw_k<<<8, 192, 0, stream>>>(js);
    }

    // 2) CSR build
    zero_k<<<(2 * NN + 255) / 256, 256, 0, stream>>>(icnt, 2 * NN);
    hist_k<<<(2 * Ec + 255) / 256, 256, 0, stream>>>(go_dst, back_dst, icnt);
    scan_a_k<<<dim3(SCB, 2), 256, 0, stream>>>(icnt, ibs);
    scan_b_k<<<2, 512, 0, stream>>>(ibs, ioff);
    scan_c_k<<<dim3(SCB, 2), 256, 0, stream>>>(icnt, ibs, ioff);
    fill_k<<<(2 * Ec + 255) / 256, 256, 0, stream>>>(go_src, go_dst, back_src, back_dst, ioff, icnt, icsr);

    auto run_rel = [&](int din, const float* srcX, const float* dstX,
                       const float* W, const float* resW, const float* bias,
                       const float* Wlft, const float* Wrgt,
                       const int* off, const int* csr,
                       const float* lW, const float* lb, const float* bnp, float* outp)
    {
        TJob jA = { srcX, W,    Wlft, nullptr, (void*)fsh, el };
        TJob jB = { dstX, resW, Wrgt, bias,    (void*)acc, er };
        dim3 g((NN + 255) / 256, 2);
        if (din == 64) transform_k<64><<<g, 256, 0, stream>>>(jA, jB, NN);
        else           transform_k<32><<<g, 256, 0, stream>>>(jA, jB, NN);
        agg_lin_k<<<(NN + 3) / 4, 256, 0, stream>>>(off, csr, el, er, fsh, acc, lW, lb, bnp, outp, NN);
    };

    // ---- layer 1 ----
    run_rel(64, emb_user, emb_item, W1,            res1,            bias1,
            aw + 0,    aw + 192,  ioff,          icsr,
            nnW1 + HD * DOUT, nnb1 + DOUT, bn1 + 4 * DOUT, hi1);          // 'go' -> items
    run_rel(64, emb_item, emb_user, W1 + 64 * HD,  res1 + 64 * HD,  bias1 + HD,
            aw + 384,  aw + 576,  ioff + NN + 1, icsr + Ec,
            nnW1, nnb1, bn1, hu1);                                         // 'back' -> users

    // ---- layer 2 ----
    run_rel(32, hu1, hi1, W2,           res2,           bias2,
            aw + 768,  aw + 960,  ioff,          icsr,
            nnW2 + HD * DOUT, nnb2 + DOUT, bn2 + 4 * DOUT, out_item);      // 'go' -> items
    run_rel(32, hi1, hu1, W2 + 32 * HD, res2 + 32 * HD, bias2 + HD,
            aw + 1152, aw + 1344, ioff + NN + 1, icsr + Ec,
            nnW2, nnb2, bn2, out_user);                                    // 'back' -> users

    (void)ibs;
}

// Round 8
// 882.120 us; speedup vs baseline: 1.5972x; 1.5972x over previous
//
#include <hip/hip_runtime.h>
#include <hip/hip_fp16.h>
#include <cmath>

#define NHEAD 3
#define HD 96          // H * D = 3 * 32
#define DOUT 32
#define SLOPE 0.01f
#define BN_EPS 1e-5f

static constexpr int NN = 100000;   // NU == NI == 100000
static constexpr int Ec = 500000;
static constexpr int SCB = (NN + 255) / 256;   // 391 chunks per relation

// ---------------- job structs ----------------
struct TJob { const void* X; const float* W; const float* Wsm; const float* bias; void* outF; float* outE; };
struct AWJob { const float* W; const float* a; float* out; int din; };
struct AWJobs { AWJob j[8]; };

// ---------------- attn-weight pre-reduction ----------------
__global__ __launch_bounds__(192)
void attw_k(AWJobs js) {
    AWJob jb = js.j[blockIdx.x];
    const int t = threadIdx.x;
    const int k = t / 3, h = t - 3 * (t / 3);
    if (k < jb.din) {
        const float* wrow = jb.W + (size_t)k * HD + h * 32;
        const float* av = jb.a + h * 32;
        float s = 0.f;
        #pragma unroll
        for (int d = 0; d < 32; ++d) s = fmaf(wrow[d], av[d], s);
        jb.out[k * 3 + h] = s;
    }
}

// ---------------- fp32 -> fp16 conversion (embeddings) ----------------
__global__ __launch_bounds__(256)
void f2h_k(const float4* __restrict__ in, uint2* __restrict__ out, int n4) {
    const int i = blockIdx.x * 256 + threadIdx.x;
    if (i < n4) {
        const float4 v = in[i];
        uint2 u;
        u.x = __builtin_bit_cast(unsigned int, __float22half2_rn(make_float2(v.x, v.y)));
        u.y = __builtin_bit_cast(unsigned int, __float22half2_rn(make_float2(v.z, v.w)));
        out[i] = u;
    }
}

// ---------------- CSR build ----------------
__global__ void zero_k(int* p, int n) {
    const int i = blockIdx.x * 256 + threadIdx.x;
    if (i < n) p[i] = 0;
}

__global__ void hist_k(const int* __restrict__ gd, const int* __restrict__ bd, int* __restrict__ cnt) {
    const int i = blockIdx.x * 256 + threadIdx.x;
    if (i < Ec) atomicAdd(&cnt[gd[i]], 1);
    else if (i < 2 * Ec) atomicAdd(&cnt[NN + bd[i - Ec]], 1);
}

__global__ __launch_bounds__(256)
void scan_a_k(const int* __restrict__ cnt, int* __restrict__ bsum) {
    const int rel = blockIdx.y, blk = blockIdx.x;
    const int i = blk * 256 + threadIdx.x;
    int v = (i < NN) ? cnt[rel * NN + i] : 0;
    #pragma unroll
    for (int d = 32; d; d >>= 1) v += __shfl_xor(v, d);
    __shared__ int ws[4];
    const int lane = threadIdx.x & 63, wid = threadIdx.x >> 6;
    if (lane == 0) ws[wid] = v;
    __syncthreads();
    if (threadIdx.x == 0) bsum[rel * SCB + blk] = ws[0] + ws[1] + ws[2] + ws[3];
}

__global__ __launch_bounds__(512)
void scan_b_k(int* __restrict__ bsum, int* __restrict__ off) {
    const int rel = blockIdx.x;
    __shared__ int ps[512];
    const int t = threadIdx.x;
    const int v = (t < SCB) ? bsum[rel * SCB + t] : 0;
    ps[t] = v;
    __syncthreads();
    for (int d = 1; d < 512; d <<= 1) {
        const int u = (t >= d) ? ps[t - d] : 0;
        __syncthreads();
        ps[t] += u;
        __syncthreads();
    }
    if (t < SCB) bsum[rel * SCB + t] = ps[t] - v;
    if (t == SCB - 1) off[rel * (NN + 1) + NN] = ps[t];
}

__global__ __launch_bounds__(256)
void scan_c_k(int* __restrict__ cnt, const int* __restrict__ bsum, int* __restrict__ off) {
    const int rel = blockIdx.y, blk = blockIdx.x;
    const int t = threadIdx.x;
    const int i = blk * 256 + t;
    const int v = (i < NN) ? cnt[rel * NN + i] : 0;
    const int lane = t & 63, wid = t >> 6;
    int incl = v;
    #pragma unroll
    for (int d = 1; d < 64; d <<= 1) {
        const int u = __shfl_up(incl, d);
        if (lane >= d) incl += u;
    }
    __shared__ int wsum[4];
    if (lane == 63) wsum[wid] = incl;
    __syncthreads();
    int base = 0;
    #pragma unroll
    for (int w = 0; w < 4; ++w) base += (w < wid) ? wsum[w] : 0;
    if (i < NN) {
        off[rel * (NN + 1) + i] = bsum[rel * SCB + blk] + base + incl - v;
        cnt[rel * NN + i] = 0;
    }
}

__global__ void fill_k(const int* __restrict__ gs, const int* __restrict__ gd,
                       const int* __restrict__ bs, const int* __restrict__ bd,
                       const int* __restrict__ off, int* __restrict__ cur, int* __restrict__ csr) {
    const int i = blockIdx.x * 256 + threadIdx.x;
    if (i < Ec) {
        const int d = gd[i];
        const int p = off[d] + atomicAdd(&cur[d], 1);
        csr[p] = gs[i];
    } else if (i < 2 * Ec) {
        const int d = bd[i - Ec];
        const int p = off[(NN + 1) + d] + atomicAdd(&cur[NN + d], 1);
        csr[Ec + p] = bs[i - Ec];
    }
}

// ---------------- dense transform (round-5 proven structure, fp16 X, fp16 out) ----------------
// node-per-thread, W via uniform s_load, acc[96] (compiler strip-mines w/ X re-reads from L2).
// Both jobs pack fp16 output; jB adds bias (residual base).
template<int DIN>
__global__ __launch_bounds__(256)
void transform_k(TJob jA, TJob jB, int N) {
    const TJob j = (blockIdx.y == 0) ? jA : jB;
    const int n = blockIdx.x * 256 + threadIdx.x;
    if (n >= N) return;
    const float* __restrict__ Wg  = j.W;
    const float* __restrict__ Wsm = j.Wsm;
    const float* __restrict__ bs  = j.bias;

    float acc[HD];
    if (bs) {
        #pragma unroll
        for (int jo = 0; jo < HD; ++jo) acc[jo] = bs[jo];     // uniform -> s_load
    } else {
        #pragma unroll
        for (int jo = 0; jo < HD; ++jo) acc[jo] = 0.f;
    }
    float e0 = 0.f, e1 = 0.f, e2 = 0.f;

    const uint2* __restrict__ xrow =
        reinterpret_cast<const uint2*>((const unsigned short*)j.X + (size_t)n * DIN);
    #pragma unroll 1
    for (int kk = 0; kk < DIN / 4; ++kk) {
        const uint2 u = xrow[kk];
        const float2 f0 = __half22float2(__builtin_bit_cast(__half2, u.x));
        const float2 f1 = __half22float2(__builtin_bit_cast(__half2, u.y));
        float xs[4] = { f0.x, f0.y, f1.x, f1.y };
        #pragma unroll
        for (int q = 0; q < 4; ++q) {
            const int k = kk * 4 + q;
            const float x = xs[q];
            e0 = fmaf(x, Wsm[k * 3 + 0], e0);
            e1 = fmaf(x, Wsm[k * 3 + 1], e1);
            e2 = fmaf(x, Wsm[k * 3 + 2], e2);
            #pragma unroll
            for (int jo = 0; jo < HD; ++jo)
                acc[jo] = fmaf(x, Wg[k * HD + jo], acc[jo]);  // uniform -> s_load
        }
    }
    j.outE[(size_t)n * 3 + 0] = e0;
    j.outE[(size_t)n * 3 + 1] = e1;
    j.outE[(size_t)n * 3 + 2] = e2;

    unsigned int* __restrict__ op = (unsigned int*)j.outF + (size_t)n * 48;
    #pragma unroll
    for (int jo = 0; jo < HD; jo += 8) {
        uint4 u;
        u.x = __builtin_bit_cast(unsigned int, __float22half2_rn(make_float2(acc[jo    ], acc[jo + 1])));
        u.y = __builtin_bit_cast(unsigned int, __float22half2_rn(make_float2(acc[jo + 2], acc[jo + 3])));
        u.z = __builtin_bit_cast(unsigned int, __float22half2_rn(make_float2(acc[jo + 4], acc[jo + 5])));
        u.w = __builtin_bit_cast(unsigned int, __float22half2_rn(make_float2(acc[jo + 6], acc[jo + 7])));
        *reinterpret_cast<uint4*>(op + jo / 2) = u;
    }
}

// ---------------- fused softmax + aggregation + linear + BN + ReLU ----------------
// Block = 4 waves = 4 dst nodes. Shfl-broadcast edge (src, w0..w2); fp16 messages +
// fp16 residual -> xLDS(fp32). Phase2: 128 threads (4 nodes x 32) lin+BN+ReLU.
// FINAL: write fp32 to d_out; else fp16 intermediate (layer-2 input).
template<bool FINAL>
__global__ __launch_bounds__(256)
void agg_lin_k(const int* __restrict__ off, const int* __restrict__ srcs,
               const float* __restrict__ el, const float* __restrict__ er,
               const __half2* __restrict__ fsh, const __half2* __restrict__ accres,
               const float* __restrict__ Wl, const float* __restrict__ bl,
               const float* __restrict__ bn, void* __restrict__ outv, int N)
{
    __shared__ float xLDS[4][100];

    const int wid  = threadIdx.x >> 6;
    const int lane = threadIdx.x & 63;
    const int node = blockIdx.x * 4 + wid;

    if (node < N) {
        const int o0 = off[node], o1 = off[node + 1];
        const int deg = o1 - o0;
        const float er0 = er[node * 3 + 0], er1 = er[node * 3 + 1], er2 = er[node * 3 + 2];
        const int h2 = lane >> 4;          // head for channel pair (2*lane, 2*lane+1), lane<48
        float a0 = 0.f, a1 = 0.f;

        if (deg <= 64) {
            // ---- fast path: 1 edge per lane, all state in registers ----
            const int p = o0 + lane;
            const bool has = p < o1;
            const int s = has ? srcs[p] : 0;
            float v0 = -INFINITY, v1 = -INFINITY, v2 = -INFINITY;
            if (has) {
                v0 = el[s * 3 + 0] + er0; v0 = v0 > 0.f ? v0 : SLOPE * v0;
                v1 = el[s * 3 + 1] + er1; v1 = v1 > 0.f ? v1 : SLOPE * v1;
                v2 = el[s * 3 + 2] + er2; v2 = v2 > 0.f ? v2 : SLOPE * v2;
            }
            float m0 = v0, m1 = v1, m2 = v2;
            #pragma unroll
            for (int d = 32; d; d >>= 1) {
                m0 = fmaxf(m0, __shfl_xor(m0, d));
                m1 = fmaxf(m1, __shfl_xor(m1, d));
                m2 = fmaxf(m2, __shfl_xor(m2, d));
            }
            const float e0x = has ? __expf(v0 - m0) : 0.f;
            const float e1x = has ? __expf(v1 - m1) : 0.f;
            const float e2x = has ? __expf(v2 - m2) : 0.f;
            float s0 = e0x, s1 = e1x, s2 = e2x;
            #pragma unroll
            for (int d = 32; d; d >>= 1) {
                s0 += __shfl_xor(s0, d); s1 += __shfl_xor(s1, d); s2 += __shfl_xor(s2, d);
            }
            const float w0 = e0x * (s0 > 0.f ? 1.f / s0 : 0.f);
            const float w1 = e1x * (s1 > 0.f ? 1.f / s1 : 0.f);
            const float w2 = e2x * (s2 > 0.f ? 1.f / s2 : 0.f);
            #pragma unroll 2
            for (int jj = 0; jj < deg; ++jj) {
                const int   sj = __shfl(s,  jj);
                const float t0 = __shfl(w0, jj);
                const float t1 = __shfl(w1, jj);
                const float t2 = __shfl(w2, jj);
                const float wgt = (h2 == 0) ? t0 : (h2 == 1) ? t1 : t2;
                if (lane < 48) {
                    const float2 f = __half22float2(fsh[(size_t)sj * 48 + lane]);
                    a0 = fmaf(f.x, wgt, a0);
                    a1 = fmaf(f.y, wgt, a1);
                }
            }
        } else {
            // ---- generic path (deg > 64), rare ----
            float m0 = -INFINITY, m1 = -INFINITY, m2 = -INFINITY;
            for (int p = o0 + lane; p < o1; p += 64) {
                const int s = srcs[p];
                float v0 = el[s * 3 + 0] + er0; v0 = v0 > 0.f ? v0 : SLOPE * v0;
                float v1 = el[s * 3 + 1] + er1; v1 = v1 > 0.f ? v1 : SLOPE * v1;
                float v2 = el[s * 3 + 2] + er2; v2 = v2 > 0.f ? v2 : SLOPE * v2;
                m0 = fmaxf(m0, v0); m1 = fmaxf(m1, v1); m2 = fmaxf(m2, v2);
            }
            #pragma unroll
            for (int d = 32; d; d >>= 1) {
                m0 = fmaxf(m0, __shfl_xor(m0, d));
                m1 = fmaxf(m1, __shfl_xor(m1, d));
                m2 = fmaxf(m2, __shfl_xor(m2, d));
            }
            float s0 = 0.f, s1 = 0.f, s2 = 0.f;
            for (int p = o0 + lane; p < o1; p += 64) {
                const int s = srcs[p];
                float v0 = el[s * 3 + 0] + er0; v0 = v0 > 0.f ? v0 : SLOPE * v0;
                float v1 = el[s * 3 + 1] + er1; v1 = v1 > 0.f ? v1 : SLOPE * v1;
                float v2 = el[s * 3 + 2] + er2; v2 = v2 > 0.f ? v2 : SLOPE * v2;
                s0 += __expf(v0 - m0); s1 += __expf(v1 - m1); s2 += __expf(v2 - m2);
            }
            #pragma unroll
            for (int d = 32; d; d >>= 1) {
                s0 += __shfl_xor(s0, d); s1 += __shfl_xor(s1, d); s2 += __shfl_xor(s2, d);
            }
            const float r0 = s0 > 0.f ? 1.f / s0 : 0.f;
            const float r1 = s1 > 0.f ? 1.f / s1 : 0.f;
            const float r2 = s2 > 0.f ? 1.f / s2 : 0.f;
            if (lane < 48) {
                const float erh = (h2 == 0) ? er0 : (h2 == 1) ? er1 : er2;
                const float mh  = (h2 == 0) ? m0  : (h2 == 1) ? m1  : m2;
                const float rh  = (h2 == 0) ? r0  : (h2 == 1) ? r1  : r2;
                for (int p = o0; p < o1; ++p) {
                    const int s = srcs[p];
                    float v = el[s * 3 + h2] + erh; v = v > 0.f ? v : SLOPE * v;
                    const float wgt = __expf(v - mh) * rh;
                    const float2 f = __half22float2(fsh[(size_t)s * 48 + lane]);
                    a0 = fmaf(f.x, wgt, a0);
                    a1 = fmaf(f.y, wgt, a1);
                }
            }
        }
        if (lane < 48) {
            const float2 rv = __half22float2(accres[(size_t)node * 48 + lane]);
            float2 xv; xv.x = a0 + rv.x; xv.y = a1 + rv.y;
            *reinterpret_cast<float2*>(&xLDS[wid][2 * lane]) = xv;
        }
    }
    __syncthreads();

    // ---- phase 2: linear(96->32) + BN + ReLU ----
    const int t = threadIdx.x;
    if (t < 128) {
        const int nd = t >> 5, o = t & 31;
        const int node2 = blockIdx.x * 4 + nd;
        if (node2 < N) {
            float y = bl[o];
            const float* xr = xLDS[nd];
            #pragma unroll 4
            for (int k = 0; k < HD; ++k)
                y = fmaf(xr[k], Wl[k * DOUT + o], y);
            const float gamma = bn[o], beta = bn[DOUT + o], mean = bn[2 * DOUT + o], var = bn[3 * DOUT + o];
            const float r = fmaxf((y - mean) * gamma * rsqrtf(var + BN_EPS) + beta, 0.f);
            if (FINAL) ((float*)outv)[(size_t)node2 * DOUT + o] = r;
            else       ((__half*)outv)[(size_t)node2 * DOUT + o] = __float2half(r);
        }
    }
}

// ---------------- host ----------------
extern "C" void kernel_launch(void* const* d_in, const int* in_sizes, int n_in,
                              void* d_out, int out_size, void* d_ws, size_t ws_size,
                              hipStream_t stream)
{
    const float* emb_user = (const float*)d_in[0];
    const float* emb_item = (const float*)d_in[1];
    const float* W1    = (const float*)d_in[2];
    const float* attn1 = (const float*)d_in[3];
    const float* res1  = (const float*)d_in[4];
    const float* bias1 = (const float*)d_in[5];
    const float* nnW1  = (const float*)d_in[6];
    const float* nnb1  = (const float*)d_in[7];
    const float* bn1   = (const float*)d_in[8];
    const float* W2    = (const float*)d_in[9];
    const float* attn2 = (const float*)d_in[10];
    const float* res2  = (const float*)d_in[11];
    const float* bias2 = (const float*)d_in[12];
    const float* nnW2  = (const float*)d_in[13];
    const float* nnb2  = (const float*)d_in[14];
    const float* bn2   = (const float*)d_in[15];
    const int* go_src   = (const int*)d_in[16];
    const int* go_dst   = (const int*)d_in[17];
    const int* back_src = (const int*)d_in[18];
    const int* back_dst = (const int*)d_in[19];

    // ---- workspace layout (~85 MB) ----
    int* icnt = (int*)d_ws;                    // 2*NN
    int* ioff = icnt + 2 * NN;                 // 2*(NN+1)
    int* icsr = ioff + 2 * (NN + 1);           // 2*Ec
    int* ibs  = icsr + 2 * Ec;                 // 2*SCB
    float* fbase = (float*)((int*)d_ws + 1400800);   // 16B-aligned float region
    float* aw    = fbase;                      // 2048
    float* p     = aw + 2048;
    __half2* fsh  = (__half2*)p;  p += (size_t)NN * 48;   // NN*96 halves (messages)
    __half2* acch = (__half2*)p;  p += (size_t)NN * 48;   // NN*96 halves (residual base)
    float* el  = p;               p += (size_t)NN * 3;
    float* er  = p;               p += (size_t)NN * 3;
    __half2* xu  = (__half2*)p;   p += (size_t)NN * 32;   // emb_user fp16 (64/node)
    __half2* xi  = (__half2*)p;   p += (size_t)NN * 32;   // emb_item fp16
    __half* hu1h = (__half*)p;    p += (size_t)NN * 16;   // layer-1 user out fp16 (32/node)
    __half* hi1h = (__half*)p;    p += (size_t)NN * 16;   // layer-1 item out fp16

    float* out_user = (float*)d_out;
    float* out_item = out_user + (size_t)NN * DOUT;

    // 1) attention pre-reduction
    {
        const float* Wm[4] = { W1, W1 + 64 * HD, W2, W2 + 32 * HD };
        const float* Am[4] = { attn1, attn1 + 192, attn2, attn2 + 192 };
        const int dins[4] = { 64, 64, 32, 32 };
        AWJobs js;
        for (int r = 0; r < 4; ++r)
            for (int s = 0; s < 2; ++s)
                js.j[r * 2 + s] = { Wm[r], Am[r] + s * HD, aw + (size_t)(r * 2 + s) * 192, dins[r] };
        attw_k<<<8, 192, 0, stream>>>(js);
    }

    // 1b) embeddings fp32 -> fp16
    f2h_k<<<(NN * 16 + 255) / 256, 256, 0, stream>>>((const float4*)emb_user, (uint2*)xu, NN * 16);
    f2h_k<<<(NN * 16 + 255) / 256, 256, 0, stream>>>((const float4*)emb_item, (uint2*)xi, NN * 16);

    // 2) CSR build
    zero_k<<<(2 * NN + 255) / 256, 256, 0, stream>>>(icnt, 2 * NN);
    hist_k<<<(2 * Ec + 255) / 256, 256, 0, stream>>>(go_dst, back_dst, icnt);
    scan_a_k<<<dim3(SCB, 2), 256, 0, stream>>>(icnt, ibs);
    scan_b_k<<<2, 512, 0, stream>>>(ibs, ioff);
    scan_c_k<<<dim3(SCB, 2), 256, 0, stream>>>(icnt, ibs, ioff);
    fill_k<<<(2 * Ec + 255) / 256, 256, 0, stream>>>(go_src, go_dst, back_src, back_dst, ioff, icnt, icsr);

    auto run_rel = [&](int din, const void* srcX, const void* dstX,
                       const float* W, const float* resW, const float* bias,
                       const float* Wlft, const float* Wrgt,
                       const int* off, const int* csr,
                       const float* lW, const float* lb, const float* bnp,
                       void* outp, bool final_out)
    {
        TJob jA = { srcX, W,    Wlft, nullptr, (void*)fsh,  el };
        TJob jB = { dstX, resW, Wrgt, bias,    (void*)acch, er };
        dim3 g((NN + 255) / 256, 2);
        if (din == 64) transform_k<64><<<g, 256, 0, stream>>>(jA, jB, NN);
        else           transform_k<32><<<g, 256, 0, stream>>>(jA, jB, NN);
        if (final_out)
            agg_lin_k<true ><<<(NN + 3) / 4, 256, 0, stream>>>(off, csr, el, er, fsh, acch, lW, lb, bnp, outp, NN);
        else
            agg_lin_k<false><<<(NN + 3) / 4, 256, 0, stream>>>(off, csr, el, er, fsh, acch, lW, lb, bnp, outp, NN);
    };

    // ---- layer 1 ----
    run_rel(64, xu, xi, W1,            res1,            bias1,
            aw + 0,    aw + 192,  ioff,          icsr,
            nnW1 + HD * DOUT, nnb1 + DOUT, bn1 + 4 * DOUT, hi1h, false);   // 'go' -> items
    run_rel(64, xi, xu, W1 + 64 * HD,  res1 + 64 * HD,  bias1 + HD,
            aw + 384,  aw + 576,  ioff + NN + 1, icsr + Ec,
            nnW1, nnb1, bn1, hu1h, false);                                  // 'back' -> users

    // ---- layer 2 ----
    run_rel(32, hu1h, hi1h, W2,           res2,           bias2,
            aw + 768,  aw + 960,  ioff,          icsr,
            nnW2 + HD * DOUT, nnb2 + DOUT, bn2 + 4 * DOUT, out_item, true); // 'go' -> items
    run_rel(32, hi1h, hu1h, W2 + 32 * HD, res2 + 32 * HD, bias2 + HD,
            aw + 1152, aw + 1344, ioff + NN + 1, icsr + Ec,
            nnW2, nnb2, bn2, out_user, true);                               // 'back' -> users

    (void)ibs;
}

// Round 9
// 855.419 us; speedup vs baseline: 1.6471x; 1.0312x over previous
//
#include <hip/hip_runtime.h>
#include <hip/hip_fp16.h>
#include <cmath>

#define NHEAD 3
#define HD 96          // H * D = 3 * 32
#define DOUT 32
#define SLOPE 0.01f
#define BN_EPS 1e-5f

static constexpr int NN = 100000;   // NU == NI == 100000
static constexpr int Ec = 500000;
static constexpr int SCB = (NN + 255) / 256;   // 391 chunks per relation

// ---------------- job structs ----------------
struct TJob { const void* X; const float* W; const float* Wsm; const float* bias; void* outF; float* outE; };
struct AWJob { const float* W; const float* a; float* out; int din; };
struct AWJobs { AWJob j[8]; };

// ---------------- attn-weight pre-reduction ----------------
__global__ __launch_bounds__(192)
void attw_k(AWJobs js) {
    AWJob jb = js.j[blockIdx.x];
    const int t = threadIdx.x;
    const int k = t / 3, h = t - 3 * (t / 3);
    if (k < jb.din) {
        const float* wrow = jb.W + (size_t)k * HD + h * 32;
        const float* av = jb.a + h * 32;
        float s = 0.f;
        #pragma unroll
        for (int d = 0; d < 32; ++d) s = fmaf(wrow[d], av[d], s);
        jb.out[k * 3 + h] = s;
    }
}

// ---------------- fp32 -> fp16 conversion (embeddings) ----------------
__global__ __launch_bounds__(256)
void f2h_k(const float4* __restrict__ in, uint2* __restrict__ out, int n4) {
    const int i = blockIdx.x * 256 + threadIdx.x;
    if (i < n4) {
        const float4 v = in[i];
        uint2 u;
        u.x = __builtin_bit_cast(unsigned int, __float22half2_rn(make_float2(v.x, v.y)));
        u.y = __builtin_bit_cast(unsigned int, __float22half2_rn(make_float2(v.z, v.w)));
        out[i] = u;
    }
}

// ---------------- CSR build ----------------
__global__ void zero_k(int* p, int n) {
    const int i = blockIdx.x * 256 + threadIdx.x;
    if (i < n) p[i] = 0;
}

__global__ void hist_k(const int* __restrict__ gd, const int* __restrict__ bd, int* __restrict__ cnt) {
    const int i = blockIdx.x * 256 + threadIdx.x;
    if (i < Ec) atomicAdd(&cnt[gd[i]], 1);
    else if (i < 2 * Ec) atomicAdd(&cnt[NN + bd[i - Ec]], 1);
}

__global__ __launch_bounds__(256)
void scan_a_k(const int* __restrict__ cnt, int* __restrict__ bsum) {
    const int rel = blockIdx.y, blk = blockIdx.x;
    const int i = blk * 256 + threadIdx.x;
    int v = (i < NN) ? cnt[rel * NN + i] : 0;
    #pragma unroll
    for (int d = 32; d; d >>= 1) v += __shfl_xor(v, d);
    __shared__ int ws[4];
    const int lane = threadIdx.x & 63, wid = threadIdx.x >> 6;
    if (lane == 0) ws[wid] = v;
    __syncthreads();
    if (threadIdx.x == 0) bsum[rel * SCB + blk] = ws[0] + ws[1] + ws[2] + ws[3];
}

__global__ __launch_bounds__(512)
void scan_b_k(int* __restrict__ bsum, int* __restrict__ off) {
    const int rel = blockIdx.x;
    __shared__ int ps[512];
    const int t = threadIdx.x;
    const int v = (t < SCB) ? bsum[rel * SCB + t] : 0;
    ps[t] = v;
    __syncthreads();
    for (int d = 1; d < 512; d <<= 1) {
        const int u = (t >= d) ? ps[t - d] : 0;
        __syncthreads();
        ps[t] += u;
        __syncthreads();
    }
    if (t < SCB) bsum[rel * SCB + t] = ps[t] - v;
    if (t == SCB - 1) off[rel * (NN + 1) + NN] = ps[t];
}

__global__ __launch_bounds__(256)
void scan_c_k(int* __restrict__ cnt, const int* __restrict__ bsum, int* __restrict__ off) {
    const int rel = blockIdx.y, blk = blockIdx.x;
    const int t = threadIdx.x;
    const int i = blk * 256 + t;
    const int v = (i < NN) ? cnt[rel * NN + i] : 0;
    const int lane = t & 63, wid = t >> 6;
    int incl = v;
    #pragma unroll
    for (int d = 1; d < 64; d <<= 1) {
        const int u = __shfl_up(incl, d);
        if (lane >= d) incl += u;
    }
    __shared__ int wsum[4];
    if (lane == 63) wsum[wid] = incl;
    __syncthreads();
    int base = 0;
    #pragma unroll
    for (int w = 0; w < 4; ++w) base += (w < wid) ? wsum[w] : 0;
    if (i < NN) {
        off[rel * (NN + 1) + i] = bsum[rel * SCB + blk] + base + incl - v;
        cnt[rel * NN + i] = 0;
    }
}

__global__ void fill_k(const int* __restrict__ gs, const int* __restrict__ gd,
                       const int* __restrict__ bs, const int* __restrict__ bd,
                       const int* __restrict__ off, int* __restrict__ cur, int* __restrict__ csr) {
    const int i = blockIdx.x * 256 + threadIdx.x;
    if (i < Ec) {
        const int d = gd[i];
        const int p = off[d] + atomicAdd(&cur[d], 1);
        csr[p] = gs[i];
    } else if (i < 2 * Ec) {
        const int d = bd[i - Ec];
        const int p = off[(NN + 1) + d] + atomicAdd(&cur[NN + d], 1);
        csr[Ec + p] = bs[i - Ec];
    }
}

// ---------------- dense transform (proven structure, fp16 X, fp16 out, el/er stride-4) ----------------
template<int DIN>
__global__ __launch_bounds__(256)
void transform_k(TJob jA, TJob jB, int N) {
    const TJob j = (blockIdx.y == 0) ? jA : jB;
    const int n = blockIdx.x * 256 + threadIdx.x;
    if (n >= N) return;
    const float* __restrict__ Wg  = j.W;
    const float* __restrict__ Wsm = j.Wsm;
    const float* __restrict__ bs  = j.bias;

    float acc[HD];
    if (bs) {
        #pragma unroll
        for (int jo = 0; jo < HD; ++jo) acc[jo] = bs[jo];     // uniform -> s_load
    } else {
        #pragma unroll
        for (int jo = 0; jo < HD; ++jo) acc[jo] = 0.f;
    }
    float e0 = 0.f, e1 = 0.f, e2 = 0.f;

    const uint2* __restrict__ xrow =
        reinterpret_cast<const uint2*>((const unsigned short*)j.X + (size_t)n * DIN);
    #pragma unroll 1
    for (int kk = 0; kk < DIN / 4; ++kk) {
        const uint2 u = xrow[kk];
        const float2 f0 = __half22float2(__builtin_bit_cast(__half2, u.x));
        const float2 f1 = __half22float2(__builtin_bit_cast(__half2, u.y));
        float xs[4] = { f0.x, f0.y, f1.x, f1.y };
        #pragma unroll
        for (int q = 0; q < 4; ++q) {
            const int k = kk * 4 + q;
            const float x = xs[q];
            e0 = fmaf(x, Wsm[k * 3 + 0], e0);
            e1 = fmaf(x, Wsm[k * 3 + 1], e1);
            e2 = fmaf(x, Wsm[k * 3 + 2], e2);
            #pragma unroll
            for (int jo = 0; jo < HD; ++jo)
                acc[jo] = fmaf(x, Wg[k * HD + jo], acc[jo]);  // uniform -> s_load
        }
    }
    float4 ev; ev.x = e0; ev.y = e1; ev.z = e2; ev.w = 0.f;
    *reinterpret_cast<float4*>(j.outE + (size_t)n * 4) = ev;   // stride-4: one dwordx4 read later

    unsigned int* __restrict__ op = (unsigned int*)j.outF + (size_t)n * 48;
    #pragma unroll
    for (int jo = 0; jo < HD; jo += 8) {
        uint4 u;
        u.x = __builtin_bit_cast(unsigned int, __float22half2_rn(make_float2(acc[jo    ], acc[jo + 1])));
        u.y = __builtin_bit_cast(unsigned int, __float22half2_rn(make_float2(acc[jo + 2], acc[jo + 3])));
        u.z = __builtin_bit_cast(unsigned int, __float22half2_rn(make_float2(acc[jo + 4], acc[jo + 5])));
        u.w = __builtin_bit_cast(unsigned int, __float22half2_rn(make_float2(acc[jo + 6], acc[jo + 7])));
        *reinterpret_cast<uint4*>(op + jo / 2) = u;
    }
}

// ---------------- fused softmax + aggregation + linear + BN + ReLU ----------------
// Block = 4 waves = 4 dst nodes. NO softmax max-pass (shift-invariance; inputs O(1)).
// el/er read as float4. Gather loop unroll-4. Phase-2 Wl staged in LDS.
template<bool FINAL>
__global__ __launch_bounds__(256)
void agg_lin_k(const int* __restrict__ off, const int* __restrict__ srcs,
               const float4* __restrict__ elv, const float4* __restrict__ erv,
               const __half2* __restrict__ fsh, const __half2* __restrict__ accres,
               const float* __restrict__ Wl, const float* __restrict__ bl,
               const float* __restrict__ bn, void* __restrict__ outv, int N)
{
    __shared__ float WlS[HD * DOUT];   // 12 KB
    __shared__ float xLDS[4][100];

    // stage Wl (phase-2 weights) into LDS; ordered by the phase-boundary barrier
    for (int i = threadIdx.x; i < HD * DOUT; i += 256) WlS[i] = Wl[i];

    const int wid  = threadIdx.x >> 6;
    const int lane = threadIdx.x & 63;
    const int node = blockIdx.x * 4 + wid;

    if (node < N) {
        const int o0 = off[node], o1 = off[node + 1];
        const int deg = o1 - o0;
        const float4 erq = erv[node];
        const float er0 = erq.x, er1 = erq.y, er2 = erq.z;
        const int h2 = lane >> 4;          // head for channel pair (2*lane, 2*lane+1), lane<48
        float a0 = 0.f, a1 = 0.f;

        if (deg <= 64) {
            // ---- fast path: 1 edge per lane, all state in registers ----
            const int p = o0 + lane;
            const bool has = p < o1;
            const int s = has ? srcs[p] : 0;
            const float4 ev = elv[s];                  // one dwordx4
            float v0 = ev.x + er0; v0 = v0 > 0.f ? v0 : SLOPE * v0;
            float v1 = ev.y + er1; v1 = v1 > 0.f ? v1 : SLOPE * v1;
            float v2 = ev.z + er2; v2 = v2 > 0.f ? v2 : SLOPE * v2;
            const float e0x = has ? __expf(v0) : 0.f;  // no max-sub: exact (shift-invariant)
            const float e1x = has ? __expf(v1) : 0.f;
            const float e2x = has ? __expf(v2) : 0.f;
            float s0 = e0x, s1 = e1x, s2 = e2x;
            #pragma unroll
            for (int d = 32; d; d >>= 1) {
                s0 += __shfl_xor(s0, d); s1 += __shfl_xor(s1, d); s2 += __shfl_xor(s2, d);
            }
            const float w0 = e0x * (s0 > 0.f ? 1.f / s0 : 0.f);
            const float w1 = e1x * (s1 > 0.f ? 1.f / s1 : 0.f);
            const float w2 = e2x * (s2 > 0.f ? 1.f / s2 : 0.f);
            #pragma unroll 4
            for (int jj = 0; jj < deg; ++jj) {
                const int   sj = __shfl(s,  jj);
                const float t0 = __shfl(w0, jj);
                const float t1 = __shfl(w1, jj);
                const float t2 = __shfl(w2, jj);
                const float wgt = (h2 == 0) ? t0 : (h2 == 1) ? t1 : t2;
                if (lane < 48) {                        // loop-invariant exec mask
                    const float2 f = __half22float2(fsh[(size_t)sj * 48 + lane]);
                    a0 = fmaf(f.x, wgt, a0);
                    a1 = fmaf(f.y, wgt, a1);
                }
            }
        } else {
            // ---- generic path (deg > 64), rare ----
            float s0 = 0.f, s1 = 0.f, s2 = 0.f;
            for (int p = o0 + lane; p < o1; p += 64) {
                const int s = srcs[p];
                const float4 ev = elv[s];
                float v0 = ev.x + er0; v0 = v0 > 0.f ? v0 : SLOPE * v0;
                float v1 = ev.y + er1; v1 = v1 > 0.f ? v1 : SLOPE * v1;
                float v2 = ev.z + er2; v2 = v2 > 0.f ? v2 : SLOPE * v2;
                s0 += __expf(v0); s1 += __expf(v1); s2 += __expf(v2);
            }
            #pragma unroll
            for (int d = 32; d; d >>= 1) {
                s0 += __shfl_xor(s0, d); s1 += __shfl_xor(s1, d); s2 += __shfl_xor(s2, d);
            }
            const float r0 = s0 > 0.f ? 1.f / s0 : 0.f;
            const float r1 = s1 > 0.f ? 1.f / s1 : 0.f;
            const float r2 = s2 > 0.f ? 1.f / s2 : 0.f;
            if (lane < 48) {
                const float erh = (h2 == 0) ? er0 : (h2 == 1) ? er1 : er2;
                const float rh  = (h2 == 0) ? r0  : (h2 == 1) ? r1  : r2;
                for (int p = o0; p < o1; ++p) {
                    const int s = srcs[p];
                    const float4 ev = elv[s];
                    float v = ((h2 == 0) ? ev.x : (h2 == 1) ? ev.y : ev.z) + erh;
                    v = v > 0.f ? v : SLOPE * v;
                    const float wgt = __expf(v) * rh;
                    const float2 f = __half22float2(fsh[(size_t)s * 48 + lane]);
                    a0 = fmaf(f.x, wgt, a0);
                    a1 = fmaf(f.y, wgt, a1);
                }
            }
        }
        if (lane < 48) {
            const float2 rv = __half22float2(accres[(size_t)node * 48 + lane]);
            float2 xv; xv.x = a0 + rv.x; xv.y = a1 + rv.y;
            *reinterpret_cast<float2*>(&xLDS[wid][2 * lane]) = xv;
        }
    }
    __syncthreads();

    // ---- phase 2: linear(96->32) + BN + ReLU ----
    const int t = threadIdx.x;
    if (t < 128) {
        const int nd = t >> 5, o = t & 31;
        const int node2 = blockIdx.x * 4 + nd;
        if (node2 < N) {
            float y = bl[o];
            const float* xr = xLDS[nd];
            #pragma unroll
            for (int k4 = 0; k4 < HD; k4 += 4) {
                const float4 xv = *reinterpret_cast<const float4*>(xr + k4);
                y = fmaf(xv.x, WlS[(k4    ) * DOUT + o], y);
                y = fmaf(xv.y, WlS[(k4 + 1) * DOUT + o], y);
                y = fmaf(xv.z, WlS[(k4 + 2) * DOUT + o], y);
                y = fmaf(xv.w, WlS[(k4 + 3) * DOUT + o], y);
            }
            const float gamma = bn[o], beta = bn[DOUT + o], mean = bn[2 * DOUT + o], var = bn[3 * DOUT + o];
            const float r = fmaxf((y - mean) * gamma * rsqrtf(var + BN_EPS) + beta, 0.f);
            if (FINAL) ((float*)outv)[(size_t)node2 * DOUT + o] = r;
            else       ((__half*)outv)[(size_t)node2 * DOUT + o] = __float2half(r);
        }
    }
}

// ---------------- host ----------------
extern "C" void kernel_launch(void* const* d_in, const int* in_sizes, int n_in,
                              void* d_out, int out_size, void* d_ws, size_t ws_size,
                              hipStream_t stream)
{
    const float* emb_user = (const float*)d_in[0];
    const float* emb_item = (const float*)d_in[1];
    const float* W1    = (const float*)d_in[2];
    const float* attn1 = (const float*)d_in[3];
    const float* res1  = (const float*)d_in[4];
    const float* bias1 = (const float*)d_in[5];
    const float* nnW1  = (const float*)d_in[6];
    const float* nnb1  = (const float*)d_in[7];
    const float* bn1   = (const float*)d_in[8];
    const float* W2    = (const float*)d_in[9];
    const float* attn2 = (const float*)d_in[10];
    const float* res2  = (const float*)d_in[11];
    const float* bias2 = (const float*)d_in[12];
    const float* nnW2  = (const float*)d_in[13];
    const float* nnb2  = (const float*)d_in[14];
    const float* bn2   = (const float*)d_in[15];
    const int* go_src   = (const int*)d_in[16];
    const int* go_dst   = (const int*)d_in[17];
    const int* back_src = (const int*)d_in[18];
    const int* back_dst = (const int*)d_in[19];

    // ---- workspace layout (~86 MB) ----
    int* icnt = (int*)d_ws;                    // 2*NN
    int* ioff = icnt + 2 * NN;                 // 2*(NN+1)
    int* icsr = ioff + 2 * (NN + 1);           // 2*Ec
    int* ibs  = icsr + 2 * Ec;                 // 2*SCB
    float* fbase = (float*)((int*)d_ws + 1400800);   // 16B-aligned float region
    float* aw    = fbase;                      // 2048
    float* p     = aw + 2048;
    __half2* fsh  = (__half2*)p;  p += (size_t)NN * 48 + 64;  // NN*96 halves (+pad for lane48-63 strays)
    __half2* acch = (__half2*)p;  p += (size_t)NN * 48;       // NN*96 halves (residual base)
    float* el  = p;               p += (size_t)NN * 4;        // stride-4 (e0,e1,e2,pad)
    float* er  = p;               p += (size_t)NN * 4;
    __half2* xu  = (__half2*)p;   p += (size_t)NN * 32;       // emb_user fp16
    __half2* xi  = (__half2*)p;   p += (size_t)NN * 32;       // emb_item fp16
    __half* hu1h = (__half*)p;    p += (size_t)NN * 16;       // layer-1 user out fp16
    __half* hi1h = (__half*)p;    p += (size_t)NN * 16;       // layer-1 item out fp16

    float* out_user = (float*)d_out;
    float* out_item = out_user + (size_t)NN * DOUT;

    // 1) attention pre-reduction
    {
        const float* Wm[4] = { W1, W1 + 64 * HD, W2, W2 + 32 * HD };
        const float* Am[4] = { attn1, attn1 + 192, attn2, attn2 + 192 };
        const int dins[4] = { 64, 64, 32, 32 };
        AWJobs js;
        for (int r = 0; r < 4; ++r)
            for (int s = 0; s < 2; ++s)
                js.j[r * 2 + s] = { Wm[r], Am[r] + s * HD, aw + (size_t)(r * 2 + s) * 192, dins[r] };
        attw_k<<<8, 192, 0, stream>>>(js);
    }

    // 1b) embeddings fp32 -> fp16
    f2h_k<<<(NN * 16 + 255) / 256, 256, 0, stream>>>((const float4*)emb_user, (uint2*)xu, NN * 16);
    f2h_k<<<(NN * 16 + 255) / 256, 256, 0, stream>>>((const float4*)emb_item, (uint2*)xi, NN * 16);

    // 2) CSR build
    zero_k<<<(2 * NN + 255) / 256, 256, 0, stream>>>(icnt, 2 * NN);
    hist_k<<<(2 * Ec + 255) / 256, 256, 0, stream>>>(go_dst, back_dst, icnt);
    scan_a_k<<<dim3(SCB, 2), 256, 0, stream>>>(icnt, ibs);
    scan_b_k<<<2, 512, 0, stream>>>(ibs, ioff);
    scan_c_k<<<dim3(SCB, 2), 256, 0, stream>>>(icnt, ibs, ioff);
    fill_k<<<(2 * Ec + 255) / 256, 256, 0, stream>>>(go_src, go_dst, back_src, back_dst, ioff, icnt, icsr);

    auto run_rel = [&](int din, const void* srcX, const void* dstX,
                       const float* W, const float* resW, const float* bias,
                       const float* Wlft, const float* Wrgt,
                       const int* off, const int* csr,
                       const float* lW, const float* lb, const float* bnp,
                       void* outp, bool final_out)
    {
        TJob jA = { srcX, W,    Wlft, nullptr, (void*)fsh,  el };
        TJob jB = { dstX, resW, Wrgt, bias,    (void*)acch, er };
        dim3 g((NN + 255) / 256, 2);
        if (din == 64) transform_k<64><<<g, 256, 0, stream>>>(jA, jB, NN);
        else           transform_k<32><<<g, 256, 0, stream>>>(jA, jB, NN);
        if (final_out)
            agg_lin_k<true ><<<(NN + 3) / 4, 256, 0, stream>>>(off, csr, (const float4*)el, (const float4*)er,
                                                               fsh, acch, lW, lb, bnp, outp, NN);
        else
            agg_lin_k<false><<<(NN + 3) / 4, 256, 0, stream>>>(off, csr, (const float4*)el, (const float4*)er,
                                                               fsh, acch, lW, lb, bnp, outp, NN);
    };

    // ---- layer 1 ----
    run_rel(64, xu, xi, W1,            res1,            bias1,
            aw + 0,    aw + 192,  ioff,          icsr,
            nnW1 + HD * DOUT, nnb1 + DOUT, bn1 + 4 * DOUT, hi1h, false);   // 'go' -> items
    run_rel(64, xi, xu, W1 + 64 * HD,  res1 + 64 * HD,  bias1 + HD,
            aw + 384,  aw + 576,  ioff + NN + 1, icsr + Ec,
            nnW1, nnb1, bn1, hu1h, false);                                  // 'back' -> users

    // ---- layer 2 ----
    run_rel(32, hu1h, hi1h, W2,           res2,           bias2,
            aw + 768,  aw + 960,  ioff,          icsr,
            nnW2 + HD * DOUT, nnb2 + DOUT, bn2 + 4 * DOUT, out_item, true); // 'go' -> items
    run_rel(32, hi1h, hu1h, W2 + 32 * HD, res2 + 32 * HD, bias2 + HD,
            aw + 1152, aw + 1344, ioff + NN + 1, icsr + Ec,
            nnW2, nnb2, bn2, out_user, true);                               // 'back' -> users

    (void)ibs;
}

// Round 10
// 609.616 us; speedup vs baseline: 2.3112x; 1.4032x over previous
//
#include <hip/hip_runtime.h>
#include <hip/hip_fp16.h>
#include <cmath>

#define NHEAD 3
#define HD 96          // H * D = 3 * 32
#define DOUT 32
#define SLOPE 0.01f
#define BN_EPS 1e-5f

static constexpr int NN = 100000;   // NU == NI == 100000
static constexpr int Ec = 500000;
static constexpr int SCB = (NN + 255) / 256;   // 391 chunks per relation

// ---------------- helpers ----------------
__device__ inline unsigned int f22h2(float a, float b) {
    return __builtin_bit_cast(unsigned int, __float22half2_rn(make_float2(a, b)));
}
__device__ inline float2 h22f2(unsigned int u) {
    return __half22float2(__builtin_bit_cast(__half2, u));
}
__device__ inline float dot2(unsigned int a, unsigned int b, float c) {
#if __has_builtin(__builtin_amdgcn_fdot2)
    typedef _Float16 h2v __attribute__((ext_vector_type(2)));
    return __builtin_amdgcn_fdot2(__builtin_bit_cast(h2v, a), __builtin_bit_cast(h2v, b), c, false);
#else
    const float2 fa = h22f2(a), fb = h22f2(b);
    return fmaf(fa.x, fb.x, fmaf(fa.y, fb.y, c));
#endif
}

// ---------------- job structs ----------------
struct TJob { const void* X; const float* W; const float* Wsm; const float* bias; void* outF; float* outE; };
struct AWJob { const float* W; const float* a; float* out; int din; };
struct AWJobs { AWJob j[8]; };

// ---------------- attn-weight pre-reduction ----------------
__global__ __launch_bounds__(192)
void attw_k(AWJobs js) {
    AWJob jb = js.j[blockIdx.x];
    const int t = threadIdx.x;
    const int k = t / 3, h = t - 3 * (t / 3);
    if (k < jb.din) {
        const float* wrow = jb.W + (size_t)k * HD + h * 32;
        const float* av = jb.a + h * 32;
        float s = 0.f;
        #pragma unroll
        for (int d = 0; d < 32; ++d) s = fmaf(wrow[d], av[d], s);
        jb.out[k * 3 + h] = s;
    }
}

// ---------------- MLP weight pack: fp32 [96][32] -> half2 [48][32] (k-pairs) ----------------
__global__ __launch_bounds__(256)
void wprep_k(const float* W0, const float* W1, const float* W2, const float* W3, unsigned int* out) {
    const float* W = (blockIdx.x == 0) ? W0 : (blockIdx.x == 1) ? W1 : (blockIdx.x == 2) ? W2 : W3;
    for (int i = threadIdx.x; i < 48 * 32; i += 256) {
        const int kp = i >> 5, o = i & 31;
        out[blockIdx.x * 1536 + i] = f22h2(W[(2 * kp) * 32 + o], W[(2 * kp + 1) * 32 + o]);
    }
}

// ---------------- fp32 -> fp16 conversion (embeddings) ----------------
__global__ __launch_bounds__(256)
void f2h_k(const float4* __restrict__ in, uint2* __restrict__ out, int n4) {
    const int i = blockIdx.x * 256 + threadIdx.x;
    if (i < n4) {
        const float4 v = in[i];
        uint2 u;
        u.x = f22h2(v.x, v.y);
        u.y = f22h2(v.z, v.w);
        out[i] = u;
    }
}

// ---------------- CSR build ----------------
__global__ void zero_k(int* p, int n) {
    const int i = blockIdx.x * 256 + threadIdx.x;
    if (i < n) p[i] = 0;
}

__global__ void hist_k(const int* __restrict__ gd, const int* __restrict__ bd, int* __restrict__ cnt) {
    const int i = blockIdx.x * 256 + threadIdx.x;
    if (i < Ec) atomicAdd(&cnt[gd[i]], 1);
    else if (i < 2 * Ec) atomicAdd(&cnt[NN + bd[i - Ec]], 1);
}

__global__ __launch_bounds__(256)
void scan_a_k(const int* __restrict__ cnt, int* __restrict__ bsum) {
    const int rel = blockIdx.y, blk = blockIdx.x;
    const int i = blk * 256 + threadIdx.x;
    int v = (i < NN) ? cnt[rel * NN + i] : 0;
    #pragma unroll
    for (int d = 32; d; d >>= 1) v += __shfl_xor(v, d);
    __shared__ int ws[4];
    const int lane = threadIdx.x & 63, wid = threadIdx.x >> 6;
    if (lane == 0) ws[wid] = v;
    __syncthreads();
    if (threadIdx.x == 0) bsum[rel * SCB + blk] = ws[0] + ws[1] + ws[2] + ws[3];
}

__global__ __launch_bounds__(512)
void scan_b_k(int* __restrict__ bsum, int* __restrict__ off) {
    const int rel = blockIdx.x;
    __shared__ int ps[512];
    const int t = threadIdx.x;
    const int v = (t < SCB) ? bsum[rel * SCB + t] : 0;
    ps[t] = v;
    __syncthreads();
    for (int d = 1; d < 512; d <<= 1) {
        const int u = (t >= d) ? ps[t - d] : 0;
        __syncthreads();
        ps[t] += u;
        __syncthreads();
    }
    if (t < SCB) bsum[rel * SCB + t] = ps[t] - v;
    if (t == SCB - 1) off[rel * (NN + 1) + NN] = ps[t];
}

__global__ __launch_bounds__(256)
void scan_c_k(int* __restrict__ cnt, const int* __restrict__ bsum, int* __restrict__ off) {
    const int rel = blockIdx.y, blk = blockIdx.x;
    const int t = threadIdx.x;
    const int i = blk * 256 + t;
    const int v = (i < NN) ? cnt[rel * NN + i] : 0;
    const int lane = t & 63, wid = t >> 6;
    int incl = v;
    #pragma unroll
    for (int d = 1; d < 64; d <<= 1) {
        const int u = __shfl_up(incl, d);
        if (lane >= d) incl += u;
    }
    __shared__ int wsum[4];
    if (lane == 63) wsum[wid] = incl;
    __syncthreads();
    int base = 0;
    #pragma unroll
    for (int w = 0; w < 4; ++w) base += (w < wid) ? wsum[w] : 0;
    if (i < NN) {
        off[rel * (NN + 1) + i] = bsum[rel * SCB + blk] + base + incl - v;
        cnt[rel * NN + i] = 0;
    }
}

__global__ void fill_k(const int* __restrict__ gs, const int* __restrict__ gd,
                       const int* __restrict__ bs, const int* __restrict__ bd,
                       const int* __restrict__ off, int* __restrict__ cur, int* __restrict__ csr) {
    const int i = blockIdx.x * 256 + threadIdx.x;
    if (i < Ec) {
        const int d = gd[i];
        const int p = off[d] + atomicAdd(&cur[d], 1);
        csr[p] = gs[i];
    } else if (i < 2 * Ec) {
        const int d = bd[i - Ec];
        const int p = off[(NN + 1) + d] + atomicAdd(&cur[NN + d], 1);
        csr[Ec + p] = bs[i - Ec];
    }
}

// ---------------- dense transform (unchanged from round 9) ----------------
template<int DIN>
__global__ __launch_bounds__(256)
void transform_k(TJob jA, TJob jB, int N) {
    const TJob j = (blockIdx.y == 0) ? jA : jB;
    const int n = blockIdx.x * 256 + threadIdx.x;
    if (n >= N) return;
    const float* __restrict__ Wg  = j.W;
    const float* __restrict__ Wsm = j.Wsm;
    const float* __restrict__ bs  = j.bias;

    float acc[HD];
    if (bs) {
        #pragma unroll
        for (int jo = 0; jo < HD; ++jo) acc[jo] = bs[jo];     // uniform -> s_load
    } else {
        #pragma unroll
        for (int jo = 0; jo < HD; ++jo) acc[jo] = 0.f;
    }
    float e0 = 0.f, e1 = 0.f, e2 = 0.f;

    const uint2* __restrict__ xrow =
        reinterpret_cast<const uint2*>((const unsigned short*)j.X + (size_t)n * DIN);
    #pragma unroll 1
    for (int kk = 0; kk < DIN / 4; ++kk) {
        const uint2 u = xrow[kk];
        const float2 f0 = h22f2(u.x);
        const float2 f1 = h22f2(u.y);
        float xs[4] = { f0.x, f0.y, f1.x, f1.y };
        #pragma unroll
        for (int q = 0; q < 4; ++q) {
            const int k = kk * 4 + q;
            const float x = xs[q];
            e0 = fmaf(x, Wsm[k * 3 + 0], e0);
            e1 = fmaf(x, Wsm[k * 3 + 1], e1);
            e2 = fmaf(x, Wsm[k * 3 + 2], e2);
            #pragma unroll
            for (int jo = 0; jo < HD; ++jo)
                acc[jo] = fmaf(x, Wg[k * HD + jo], acc[jo]);  // uniform -> s_load
        }
    }
    float4 ev; ev.x = e0; ev.y = e1; ev.z = e2; ev.w = 0.f;
    *reinterpret_cast<float4*>(j.outE + (size_t)n * 4) = ev;

    unsigned int* __restrict__ op = (unsigned int*)j.outF + (size_t)n * 48;
    #pragma unroll
    for (int jo = 0; jo < HD; jo += 8) {
        uint4 u;
        u.x = f22h2(acc[jo    ], acc[jo + 1]);
        u.y = f22h2(acc[jo + 2], acc[jo + 3]);
        u.z = f22h2(acc[jo + 4], acc[jo + 5]);
        u.w = f22h2(acc[jo + 6], acc[jo + 7]);
        *reinterpret_cast<uint4*>(op + jo / 2) = u;
    }
}

// ---------------- fused softmax + aggregation + linear + BN + ReLU ----------------
// Block = 512 thr = 8 waves = 16 dst nodes (2 per wave, 32-lane halves).
// Fast path (deg<=32): edge-per-lane softmax in half-wave; gather = 2 edges x 12
// channel-lanes x 16B loads; eg-pair shfl reduce. Phase2: all 512 threads,
// packed-fp16 dot2 linear (W pre-packed half2[48][32] in LDS).
template<bool FINAL>
__global__ __launch_bounds__(512)
void agg_lin_k(const int* __restrict__ off, const int* __restrict__ srcs,
               const float4* __restrict__ elv, const float4* __restrict__ erv,
               const unsigned short* __restrict__ fsh, const unsigned short* __restrict__ accres,
               const unsigned int* __restrict__ Wh, const float* __restrict__ bl,
               const float* __restrict__ bn, void* __restrict__ outv, int N)
{
    __shared__ unsigned int WhS[48 * 32];      // 6 KB packed half2 weights
    __shared__ unsigned int xLDSh[16][48];     // 3 KB aggregated rows as half2

    for (int i = threadIdx.x; i < 48 * 32; i += 512) WhS[i] = Wh[i];

    const int lane = threadIdx.x & 63;
    const int hl   = lane & 31;                // lane within half-wave
    const int hb   = lane & 32;                // half base (0 or 32)
    const int slot = threadIdx.x >> 5;         // 0..15 node slot in block
    const int node = blockIdx.x * 16 + slot;

    if (node < N) {
        const int o0 = off[node], o1 = off[node + 1];
        const int deg = o1 - o0;
        const float4 erq = erv[node];
        const float er0 = erq.x, er1 = erq.y, er2 = erq.z;

        if (deg <= 32) {
            // ---- fast path ----
            const int p = o0 + hl;
            const bool has = p < o1;
            const int s = has ? srcs[p] : 0;
            const float4 ev = elv[s];
            float v0 = ev.x + er0; v0 = v0 > 0.f ? v0 : SLOPE * v0;
            float v1 = ev.y + er1; v1 = v1 > 0.f ? v1 : SLOPE * v1;
            float v2 = ev.z + er2; v2 = v2 > 0.f ? v2 : SLOPE * v2;
            const float e0x = has ? __expf(v0) : 0.f;   // shift-invariant: no max pass
            const float e1x = has ? __expf(v1) : 0.f;
            const float e2x = has ? __expf(v2) : 0.f;
            float s0 = e0x, s1 = e1x, s2 = e2x;
            #pragma unroll
            for (int d = 16; d; d >>= 1) {              // stays within 32-lane half
                s0 += __shfl_xor(s0, d); s1 += __shfl_xor(s1, d); s2 += __shfl_xor(s2, d);
            }
            const float w0 = e0x * (s0 > 0.f ? 1.f / s0 : 0.f);
            const float w1 = e1x * (s1 > 0.f ? 1.f / s1 : 0.f);
            const float w2 = e2x * (s2 > 0.f ? 1.f / s2 : 0.f);

            const int cp = hl >> 1, eg = hl & 1;
            float a0 = 0.f, a1 = 0.f, a2 = 0.f, a3 = 0.f, a4 = 0.f, a5 = 0.f, a6 = 0.f, a7 = 0.f;
            #pragma unroll 2
            for (int jj = 0; jj < deg; jj += 2) {
                const int sl = hb | (jj + eg);
                const int   sj = __shfl(s,  sl);
                const float t0 = __shfl(w0, sl);
                const float t1 = __shfl(w1, sl);
                const float t2 = __shfl(w2, sl);
                const float wgt = (cp < 4) ? t0 : (cp < 8) ? t1 : t2;
                if (cp < 12 && wgt != 0.f) {            // masks invalid tail edges too
                    const uint4 u = *reinterpret_cast<const uint4*>(fsh + (size_t)sj * 96 + cp * 8);
                    float2 f;
                    f = h22f2(u.x); a0 = fmaf(f.x, wgt, a0); a1 = fmaf(f.y, wgt, a1);
                    f = h22f2(u.y); a2 = fmaf(f.x, wgt, a2); a3 = fmaf(f.y, wgt, a3);
                    f = h22f2(u.z); a4 = fmaf(f.x, wgt, a4); a5 = fmaf(f.y, wgt, a5);
                    f = h22f2(u.w); a6 = fmaf(f.x, wgt, a6); a7 = fmaf(f.y, wgt, a7);
                }
            }
            // reduce across eg pairs
            a0 += __shfl_xor(a0, 1); a1 += __shfl_xor(a1, 1);
            a2 += __shfl_xor(a2, 1); a3 += __shfl_xor(a3, 1);
            a4 += __shfl_xor(a4, 1); a5 += __shfl_xor(a5, 1);
            a6 += __shfl_xor(a6, 1); a7 += __shfl_xor(a7, 1);
            if (eg == 0 && cp < 12) {
                const uint4 r = *reinterpret_cast<const uint4*>(accres + (size_t)node * 96 + cp * 8);
                float2 q;
                q = h22f2(r.x); a0 += q.x; a1 += q.y;
                q = h22f2(r.y); a2 += q.x; a3 += q.y;
                q = h22f2(r.z); a4 += q.x; a5 += q.y;
                q = h22f2(r.w); a6 += q.x; a7 += q.y;
                uint4 o4;
                o4.x = f22h2(a0, a1); o4.y = f22h2(a2, a3);
                o4.z = f22h2(a4, a5); o4.w = f22h2(a6, a7);
                *reinterpret_cast<uint4*>(&xLDSh[slot][cp * 4]) = o4;
            }
        } else {
            // ---- generic path (deg > 32), essentially never for Poisson(5) ----
            float s0 = 0.f, s1 = 0.f, s2 = 0.f;
            for (int p = o0 + hl; p < o1; p += 32) {
                const int s = srcs[p];
                const float4 ev = elv[s];
                float v0 = ev.x + er0; v0 = v0 > 0.f ? v0 : SLOPE * v0;
                float v1 = ev.y + er1; v1 = v1 > 0.f ? v1 : SLOPE * v1;
                float v2 = ev.z + er2; v2 = v2 > 0.f ? v2 : SLOPE * v2;
                s0 += __expf(v0); s1 += __expf(v1); s2 += __expf(v2);
            }
            #pragma unroll
            for (int d = 16; d; d >>= 1) {
                s0 += __shfl_xor(s0, d); s1 += __shfl_xor(s1, d); s2 += __shfl_xor(s2, d);
            }
            const float r0 = s0 > 0.f ? 1.f / s0 : 0.f;
            const float r1 = s1 > 0.f ? 1.f / s1 : 0.f;
            const float r2 = s2 > 0.f ? 1.f / s2 : 0.f;
            if (hl < 12) {
                const int cp = hl, h = hl >> 2;
                const float erh = (h == 0) ? er0 : (h == 1) ? er1 : er2;
                const float rh  = (h == 0) ? r0  : (h == 1) ? r1  : r2;
                float a0 = 0.f, a1 = 0.f, a2 = 0.f, a3 = 0.f, a4 = 0.f, a5 = 0.f, a6 = 0.f, a7 = 0.f;
                for (int p = o0; p < o1; ++p) {
                    const int s = srcs[p];
                    const float4 ev = elv[s];
                    float v = ((h == 0) ? ev.x : (h == 1) ? ev.y : ev.z) + erh;
                    v = v > 0.f ? v : SLOPE * v;
                    const float wgt = __expf(v) * rh;
                    const uint4 u = *reinterpret_cast<const uint4*>(fsh + (size_t)s * 96 + cp * 8);
                    float2 f;
                    f = h22f2(u.x); a0 = fmaf(f.x, wgt, a0); a1 = fmaf(f.y, wgt, a1);
                    f = h22f2(u.y); a2 = fmaf(f.x, wgt, a2); a3 = fmaf(f.y, wgt, a3);
                    f = h22f2(u.z); a4 = fmaf(f.x, wgt, a4); a5 = fmaf(f.y, wgt, a5);
                    f = h22f2(u.w); a6 = fmaf(f.x, wgt, a6); a7 = fmaf(f.y, wgt, a7);
                }
                const uint4 r = *reinterpret_cast<const uint4*>(accres + (size_t)node * 96 + cp * 8);
                float2 q;
                q = h22f2(r.x); a0 += q.x; a1 += q.y;
                q = h22f2(r.y); a2 += q.x; a3 += q.y;
                q = h22f2(r.z); a4 += q.x; a5 += q.y;
                q = h22f2(r.w); a6 += q.x; a7 += q.y;
                uint4 o4;
                o4.x = f22h2(a0, a1); o4.y = f22h2(a2, a3);
                o4.z = f22h2(a4, a5); o4.w = f22h2(a6, a7);
                *reinterpret_cast<uint4*>(&xLDSh[slot][cp * 4]) = o4;
            }
        }
    }
    __syncthreads();

    // ---- phase 2: linear(96->32) via packed dot2 + BN + ReLU; all 512 threads ----
    const int t = threadIdx.x;
    const int nd = t >> 5, o = t & 31;
    const int node2 = blockIdx.x * 16 + nd;
    if (node2 < N) {
        float y = bl[o];
        const unsigned int* xr = xLDSh[nd];
        #pragma unroll
        for (int kq = 0; kq < 12; ++kq) {
            const uint4 xq = *reinterpret_cast<const uint4*>(&xr[kq * 4]);
            y = dot2(xq.x, WhS[(kq * 4 + 0) * 32 + o], y);
            y = dot2(xq.y, WhS[(kq * 4 + 1) * 32 + o], y);
            y = dot2(xq.z, WhS[(kq * 4 + 2) * 32 + o], y);
            y = dot2(xq.w, WhS[(kq * 4 + 3) * 32 + o], y);
        }
        const float gamma = bn[o], beta = bn[DOUT + o], mean = bn[2 * DOUT + o], var = bn[3 * DOUT + o];
        const float r = fmaxf((y - mean) * gamma * rsqrtf(var + BN_EPS) + beta, 0.f);
        if (FINAL) ((float*)outv)[(size_t)node2 * DOUT + o] = r;
        else       ((__half*)outv)[(size_t)node2 * DOUT + o] = __float2half(r);
    }
}

// ---------------- host ----------------
extern "C" void kernel_launch(void* const* d_in, const int* in_sizes, int n_in,
                              void* d_out, int out_size, void* d_ws, size_t ws_size,
                              hipStream_t stream)
{
    const float* emb_user = (const float*)d_in[0];
    const float* emb_item = (const float*)d_in[1];
    const float* W1    = (const float*)d_in[2];
    const float* attn1 = (const float*)d_in[3];
    const float* res1  = (const float*)d_in[4];
    const float* bias1 = (const float*)d_in[5];
    const float* nnW1  = (const float*)d_in[6];
    const float* nnb1  = (const float*)d_in[7];
    const float* bn1   = (const float*)d_in[8];
    const float* W2    = (const float*)d_in[9];
    const float* attn2 = (const float*)d_in[10];
    const float* res2  = (const float*)d_in[11];
    const float* bias2 = (const float*)d_in[12];
    const float* nnW2  = (const float*)d_in[13];
    const float* nnb2  = (const float*)d_in[14];
    const float* bn2   = (const float*)d_in[15];
    const int* go_src   = (const int*)d_in[16];
    const int* go_dst   = (const int*)d_in[17];
    const int* back_src = (const int*)d_in[18];
    const int* back_dst = (const int*)d_in[19];

    // ---- workspace layout (~86 MB) ----
    int* icnt = (int*)d_ws;                    // 2*NN
    int* ioff = icnt + 2 * NN;                 // 2*(NN+1)
    int* icsr = ioff + 2 * (NN + 1);           // 2*Ec
    int* ibs  = icsr + 2 * Ec;                 // 2*SCB
    float* fbase = (float*)((int*)d_ws + 1400800);   // 16B-aligned float region
    float* aw    = fbase;                      // 2048
    unsigned int* whb = (unsigned int*)(aw + 2048);  // 4*1536 packed MLP weights
    float* p     = aw + 2048 + 6144;
    unsigned short* fsh  = (unsigned short*)p;  p += (size_t)NN * 48 + 64;  // NN*96 halves (messages)
    unsigned short* acch = (unsigned short*)p;  p += (size_t)NN * 48;       // NN*96 halves (residual)
    float* el  = p;               p += (size_t)NN * 4;        // stride-4 (e0,e1,e2,pad)
    float* er  = p;               p += (size_t)NN * 4;
    __half2* xu  = (__half2*)p;   p += (size_t)NN * 32;       // emb_user fp16
    __half2* xi  = (__half2*)p;   p += (size_t)NN * 32;       // emb_item fp16
    __half* hu1h = (__half*)p;    p += (size_t)NN * 16;       // layer-1 user out fp16
    __half* hi1h = (__half*)p;    p += (size_t)NN * 16;       // layer-1 item out fp16

    float* out_user = (float*)d_out;
    float* out_item = out_user + (size_t)NN * DOUT;

    // 1) attention pre-reduction + MLP weight packing
    {
        const float* Wm[4] = { W1, W1 + 64 * HD, W2, W2 + 32 * HD };
        const float* Am[4] = { attn1, attn1 + 192, attn2, attn2 + 192 };
        const int dins[4] = { 64, 64, 32, 32 };
        AWJobs js;
        for (int r = 0; r < 4; ++r)
            for (int s = 0; s < 2; ++s)
                js.j[r * 2 + s] = { Wm[r], Am[r] + s * HD, aw + (size_t)(r * 2 + s) * 192, dins[r] };
        attw_k<<<8, 192, 0, stream>>>(js);
    }
    wprep_k<<<4, 256, 0, stream>>>(nnW1 + HD * DOUT, nnW1, nnW2 + HD * DOUT, nnW2, whb);

    // 1b) embeddings fp32 -> fp16
    f2h_k<<<(NN * 16 + 255) / 256, 256, 0, stream>>>((const float4*)emb_user, (uint2*)xu, NN * 16);
    f2h_k<<<(NN * 16 + 255) / 256, 256, 0, stream>>>((const float4*)emb_item, (uint2*)xi, NN * 16);

    // 2) CSR build
    zero_k<<<(2 * NN + 255) / 256, 256, 0, stream>>>(icnt, 2 * NN);
    hist_k<<<(2 * Ec + 255) / 256, 256, 0, stream>>>(go_dst, back_dst, icnt);
    scan_a_k<<<dim3(SCB, 2), 256, 0, stream>>>(icnt, ibs);
    scan_b_k<<<2, 512, 0, stream>>>(ibs, ioff);
    scan_c_k<<<dim3(SCB, 2), 256, 0, stream>>>(icnt, ibs, ioff);
    fill_k<<<(2 * Ec + 255) / 256, 256, 0, stream>>>(go_src, go_dst, back_src, back_dst, ioff, icnt, icsr);

    auto run_rel = [&](int din, const void* srcX, const void* dstX,
                       const float* W, const float* resW, const float* bias,
                       const float* Wlft, const float* Wrgt,
                       const int* off, const int* csr,
                       const unsigned int* Whp, const float* lb, const float* bnp,
                       void* outp, bool final_out)
    {
        TJob jA = { srcX, W,    Wlft, nullptr, (void*)fsh,  el };
        TJob jB = { dstX, resW, Wrgt, bias,    (void*)acch, er };
        dim3 g((NN + 255) / 256, 2);
        if (din == 64) transform_k<64><<<g, 256, 0, stream>>>(jA, jB, NN);
        else           transform_k<32><<<g, 256, 0, stream>>>(jA, jB, NN);
        if (final_out)
            agg_lin_k<true ><<<(NN + 15) / 16, 512, 0, stream>>>(off, csr, (const float4*)el, (const float4*)er,
                                                                 fsh, acch, Whp, lb, bnp, outp, NN);
        else
            agg_lin_k<false><<<(NN + 15) / 16, 512, 0, stream>>>(off, csr, (const float4*)el, (const float4*)er,
                                                                 fsh, acch, Whp, lb, bnp, outp, NN);
    };

    // ---- layer 1 ----
    run_rel(64, xu, xi, W1,            res1,            bias1,
            aw + 0,    aw + 192,  ioff,          icsr,
            whb + 0,    nnb1 + DOUT, bn1 + 4 * DOUT, hi1h, false);   // 'go' -> items
    run_rel(64, xi, xu, W1 + 64 * HD,  res1 + 64 * HD,  bias1 + HD,
            aw + 384,  aw + 576,  ioff + NN + 1, icsr + Ec,
            whb + 1536, nnb1, bn1, hu1h, false);                      // 'back' -> users

    // ---- layer 2 ----
    run_rel(32, hu1h, hi1h, W2,           res2,           bias2,
            aw + 768,  aw + 960,  ioff,          icsr,
            whb + 3072, nnb2 + DOUT, bn2 + 4 * DOUT, out_item, true); // 'go' -> items
    run_rel(32, hi1h, hu1h, W2 + 32 * HD, res2 + 32 * HD, bias2 + HD,
            aw + 1152, aw + 1344, ioff + NN + 1, icsr + Ec,
            whb + 4608, nnb2, bn2, out_user, true);                   // 'back' -> users

    (void)ibs;
}